// Round 12
// baseline (622.984 us; speedup 1.0000x reference)
//
#include <hip/hip_runtime.h>
#include <hip/hip_fp16.h>
#include <math.h>

typedef _Float16 f16;
typedef _Float16 f16x4 __attribute__((ext_vector_type(4)));
typedef _Float16 f16x8 __attribute__((ext_vector_type(8)));
typedef float f32x4 __attribute__((ext_vector_type(4)));

#define GLOAD_LDS16(g, l)                                                                  \
    __builtin_amdgcn_global_load_lds((const __attribute__((address_space(1))) void*)(g),   \
                                     (__attribute__((address_space(3))) void*)(l), 16, 0, 0)

// Three-source f32 -> f16 cast (W only now), 16 elems/thread/iter.
__global__ __launch_bounds__(256) void cast3_kernel(const float* __restrict__ s0,
                                                    const float* __restrict__ s1,
                                                    const float* __restrict__ s2,
                                                    f16* d0, f16* d1, f16* d2, int n16each)
{
    const int z = blockIdx.z;
    const float* src = (z == 0) ? s0 : (z == 1) ? s1 : s2;
    f16* dst = (z == 0) ? d0 : (z == 1) ? d1 : d2;
    const int stride = gridDim.x * blockDim.x;
    for (int i = blockIdx.x * blockDim.x + threadIdx.x; i < n16each; i += stride) {
        const float4* sp = (const float4*)(src + (long long)i * 16);
        float4 a = sp[0], b = sp[1], c = sp[2], d4 = sp[3];
        f16x8 lo = {(f16)a.x, (f16)a.y, (f16)a.z, (f16)a.w,
                    (f16)b.x, (f16)b.y, (f16)b.z, (f16)b.w};
        f16x8 hi = {(f16)c.x, (f16)c.y, (f16)c.z, (f16)c.w,
                    (f16)d4.x, (f16)d4.y, (f16)d4.z, (f16)d4.w};
        f16x8* dp = (f16x8*)(dst + (long long)i * 16);
        dp[0] = lo;
        dp[1] = hi;
    }
}

// ============================================================================
// 256x128 tile NT GEMM, BK=64, 512 threads (8 waves 4Mx2N), SINGLE-buffered
// (m97 regime, r10-proven: 953 TF, 0 bank conflicts).
// AF32=1: A operand is f32 in global memory; staged raw via global_load_lds
//   (256 rows x 64 k x 4B = 64 KiB), converted f32->f16 at frag-read time
//   (identical numerics to a separate cast pass).  Swizzle: 32B-granular XOR
//   (col ^ ((row&7)<<5)) on 256B rows -> 2-way conflicts (free).
// TRANSC=1: epilogue writes C transposed per-batch (vT[b][o][s]) via LDS retile.
// C[M,N] = A[M,K] * B[N,K](f16)^T.  M % 256 == 0, N % 128 == 0, K % 64 == 0.
// Grid: dim3(nwg, 1, nz), nwg % 8 == 0; gx = N/128.
// ============================================================================
template <int OUTF16, int TRANSC, int AF32>
__global__ __launch_bounds__(512, 2) void gemm_nt_k(
    const void* __restrict__ Ab, const f16* __restrict__ Bb, void* __restrict__ Cb,
    int K, int lda, int ldb, int ldc,
    long long sA, long long sB, long long sC, int gx)
{
    // A region: AF32 ? 64 KiB (256 x 256B rows) : 32 KiB (256 x 128B rows);
    // B region: 16 KiB (128 x 128B rows).  Epilogue (TRANSC) reuses as [128][136].
    __shared__ __align__(16) f16 smem[AF32 ? (256 * 128 + 128 * 64) : (256 * 64 + 128 * 64)];
    constexpr int B_OFF_E = AF32 ? 256 * 128 : 256 * 64;     // f16 elems
    constexpr int B_OFF_B = B_OFF_E * 2;                     // bytes

    // XCD-aware bijective swizzle (nwg % 8 == 0).
    const int nwg = gridDim.x;
    const int swz = (blockIdx.x & 7) * (nwg >> 3) + (blockIdx.x >> 3);
    const int bx = swz % gx, by = swz / gx;

    const int z = blockIdx.z;
    constexpr int esz = AF32 ? 4 : 2;
    const char* pA = (const char*)Ab + ((long long)z * sA + (long long)by * 256 * lda) * esz;
    const char* pB = (const char*)(Bb + z * sB + (long long)bx * 128 * ldb);
    const long long ldaB = (long long)lda * esz, ldb2 = (long long)ldb * 2;

    const int tid = threadIdx.x;
    const int w = tid >> 6, l = tid & 63;
    const int wr = w >> 1, wc = w & 1;          // 4M x 2N wave grid, wave tile 64x64

    f32x4 acc[4][4];
#pragma unroll
    for (int i = 0; i < 4; i++)
#pragma unroll
        for (int j = 0; j < 4; j++) acc[i][j] = (f32x4){0.f, 0.f, 0.f, 0.f};

    const int lr = l & 15;          // frag row within 16
    const int lkb = (l >> 4) * 16;  // frag k sub-offset in f16 bytes

    // f16 frag reads: addr = row*128 + (kbyte ^ ((row&7)<<4)), kbyte in [0,128).
#define FRAG_A16(row, kbyte)                                                              \
    (*(const f16x8*)((const char*)&smem[0] + ((row) * 128) + ((kbyte) ^ (((row) & 7) << 4))))
#define FRAG_B(row, kbyte)                                                                \
    (*(const f16x8*)((const char*)&smem[0] + B_OFF_B + ((row) * 128) + ((kbyte) ^ (((row) & 7) << 4))))

    const int nt = K >> 6;
    for (int t = 0; t < nt; ++t) {
        const long long kb = (long long)t * 64 * esz;   // byte offset of this K-tile in A rows
        // STAGE A.  AF32: 8 chunks/thread over 256B rows, 32B-XOR; else r10 path.
        if (AF32) {
#pragma unroll
            for (int i = 0; i < 8; i++) {
                const int c = i * 512 + tid;
                const int row = c >> 4;
                const int col = ((c & 15) * 16) ^ ((row & 7) << 5);
                GLOAD_LDS16(pA + (long long)row * ldaB + kb + col, &smem[(long long)c * 8]);
            }
        } else {
#pragma unroll
            for (int i = 0; i < 4; i++) {
                const int c = i * 512 + tid;
                const int row = c >> 3;
                const int col = ((c & 7) * 16) ^ ((row & 7) << 4);
                GLOAD_LDS16(pA + (long long)row * ldaB + kb + col, &smem[(long long)c * 8]);
            }
        }
        // STAGE B (always f16): 2 chunks/thread.
        {
            const long long kbB = (long long)t * 128;
#pragma unroll
            for (int i = 0; i < 2; i++) {
                const int c = i * 512 + tid;
                const int row = c >> 3;
                const int col = ((c & 7) * 16) ^ ((row & 7) << 4);
                GLOAD_LDS16(pB + (long long)row * ldb2 + kbB + col, &smem[B_OFF_E + (long long)c * 8]);
            }
        }
        __syncthreads();   // drains vmcnt (gload_lds) + publishes tile

        f16x8 bf[4][2], af[4][2];
#pragma unroll
        for (int fc = 0; fc < 4; fc++)
#pragma unroll
            for (int ks = 0; ks < 2; ks++)
                bf[fc][ks] = FRAG_B(wc * 64 + fc * 16 + lr, ks * 64 + lkb);
#pragma unroll
        for (int fq = 0; fq < 4; fq++)
#pragma unroll
            for (int ks = 0; ks < 2; ks++) {
                const int row = wr * 64 + fq * 16 + lr;
                if (AF32) {
                    // f32 frag: 32B at byte 2*(ks*64+lkb), XOR-swizzled at 32B grain.
                    const int g0 = 2 * (ks * 64 + lkb);
                    const char* base = (const char*)&smem[0] + row * 256 + ((g0) ^ ((row & 7) << 5));
                    float4 lo = *(const float4*)(base);
                    float4 hi = *(const float4*)(base + 16);
                    af[fq][ks] = (f16x8){(f16)lo.x, (f16)lo.y, (f16)lo.z, (f16)lo.w,
                                         (f16)hi.x, (f16)hi.y, (f16)hi.z, (f16)hi.w};
                } else {
                    af[fq][ks] = FRAG_A16(row, ks * 64 + lkb);
                }
            }

#pragma unroll
        for (int fq = 0; fq < 4; fq++)
#pragma unroll
            for (int fc = 0; fc < 4; fc++)
#pragma unroll
                for (int ks = 0; ks < 2; ks++)
                    acc[fq][fc] = __builtin_amdgcn_mfma_f32_16x16x32_f16(
                        af[fq][ks], bf[fc][ks], acc[fq][fc], 0, 0, 0);

        __syncthreads();   // all reads done before next STAGE overwrites
    }
#undef FRAG_A16
#undef FRAG_B

    // C/D 16x16 layout: col = lane&15, row = (lane>>4)*4 + i  (HW-verified)
    const int row_l = (l >> 4) * 4;
    const long long gr0 = (long long)by * 256 + wr * 64;
    const int gc0 = bx * 128 + wc * 64;

    if (TRANSC) {
        // Write vT[b][o][s]; block covers flat rows [by*256,+256) (within one
        // batch) and cols [bx*128,+128).  LDS retile [128 o][136 s], 2 passes.
        const long long blk_r0 = (long long)by * 256;
        const int b = (int)(blk_r0 >> 11);
        const int s_base = (int)(blk_r0 & 2047);
        f16* vTp = (f16*)Cb + (long long)b * 1024 * 2048;
#pragma unroll
        for (int h = 0; h < 2; h++) {
            __syncthreads();
            if ((wr >> 1) == h) {
                const int s64 = (wr & 1) * 64;
#pragma unroll
                for (int fq = 0; fq < 4; fq++)
#pragma unroll
                    for (int fc = 0; fc < 4; fc++)
#pragma unroll
                        for (int i = 0; i < 4; i++)
                            smem[(wc * 64 + fc * 16 + lr) * 136 + s64 + fq * 16 + row_l + i] =
                                (f16)acc[fq][fc][i];
            }
            __syncthreads();
#pragma unroll
            for (int j = 0; j < 4; j++) {
                const int c = j * 512 + tid;
                const int o = c >> 4, s8 = (c & 15) * 8;
                f16x8 vv = *(const f16x8*)&smem[o * 136 + s8];
                *(f16x8*)&vTp[((long long)(bx * 128 + o)) * 2048 + s_base + h * 128 + s8] = vv;
            }
        }
    } else if (OUTF16) {
        f16* C = (f16*)Cb + z * sC;
#pragma unroll
        for (int fq = 0; fq < 4; fq++)
#pragma unroll
            for (int fc = 0; fc < 4; fc++)
#pragma unroll
                for (int i = 0; i < 4; i++)
                    C[(gr0 + fq * 16 + row_l + i) * ldc + gc0 + fc * 16 + lr] = (f16)acc[fq][fc][i];
    } else {
        float* C = (float*)Cb + z * sC;
#pragma unroll
        for (int fq = 0; fq < 4; fq++)
#pragma unroll
            for (int fc = 0; fc < 4; fc++)
#pragma unroll
                for (int i = 0; i < 4; i++)
                    C[(gr0 + fq * 16 + row_l + i) * ldc + gc0 + fc * 16 + lr] = acc[fq][fc][i];
    }
}

__device__ __forceinline__ float wred_max(float v) {
#pragma unroll
    for (int o = 32; o > 0; o >>= 1) v = fmaxf(v, __shfl_xor(v, o));
    return v;
}
__device__ __forceinline__ float wred_sum(float v) {
#pragma unroll
    for (int o = 32; o > 0; o >>= 1) v += __shfl_xor(v, o);
    return v;
}

// In-place masked softmax over each 2048-wide score row (fp16).
__global__ __launch_bounds__(256) void softmax_kernel(f16* __restrict__ Sm, const int* __restrict__ mask)
{
    const long long row = blockIdx.x;
    const int b = (int)(row >> 11);
    f16* Srow = Sm + row * 2048;
    const int* mrow = mask + b * 2048;
    const int t = threadIdx.x;
    const int w = t >> 6, l = t & 63;

    f16x8 sv = *(const f16x8*)(Srow + t * 8);
    int4 m0 = *(const int4*)(mrow + t * 8);
    int4 m1 = *(const int4*)(mrow + t * 8 + 4);
    int mk[8] = {m0.x, m0.y, m0.z, m0.w, m1.x, m1.y, m1.z, m1.w};
    float v[8];
#pragma unroll
    for (int j = 0; j < 8; j++) v[j] = (float)sv[j];

    float mx = -INFINITY;
#pragma unroll
    for (int j = 0; j < 8; j++) if (mk[j]) mx = fmaxf(mx, v[j]);
    mx = wred_max(mx);
    __shared__ float redm[4], reds[4];
    if (l == 0) redm[w] = mx;
    __syncthreads();
    mx = fmaxf(fmaxf(redm[0], redm[1]), fmaxf(redm[2], redm[3]));

    if (mx == -INFINITY) {
        // reference: all scores == MASK_FILL -> softmax is exactly uniform
        const f16 u = (f16)(1.0f / 2048.0f);
        f16x8 pv;
#pragma unroll
        for (int j = 0; j < 8; j++) pv[j] = u;
        *(f16x8*)(Srow + t * 8) = pv;
        return;
    }

    float e[8];
    float s = 0.f;
#pragma unroll
    for (int j = 0; j < 8; j++) { e[j] = mk[j] ? expf(v[j] - mx) : 0.f; s += e[j]; }
    s = wred_sum(s);
    if (l == 0) reds[w] = s;
    __syncthreads();
    s = reds[0] + reds[1] + reds[2] + reds[3];
    const float inv = 1.0f / s;
    f16x8 pv;
#pragma unroll
    for (int j = 0; j < 8; j++) pv[j] = (f16)(e[j] * inv);
    *(f16x8*)(Srow + t * 8) = pv;
}

extern "C" void kernel_launch(void* const* d_in, const int* in_sizes, int n_in,
                              void* d_out, int out_size, void* d_ws, size_t ws_size,
                              hipStream_t stream)
{
    const float* query = (const float*)d_in[0];
    const float* keyi  = (const float*)d_in[1];
    const float* value = (const float*)d_in[2];
    const float* Wq    = (const float*)d_in[3];
    const float* Wk    = (const float*)d_in[4];
    const float* Wv    = (const float*)d_in[5];
    const int*   mask  = (const int*)d_in[6];
    float* out = (float*)d_out;

    // ws: 5 slots of SH f16 = 167.8 MB.  Lifetimes (X casts eliminated —
    // projections read f32 inputs directly via AF32 staging):
    //   slot0: P-low ; slot1: wh (6 MB, dead after k-proj) -> P-high ;
    //   slot2: q ; slot3: k ; slot4: vT (v-proj TRANSC epilogue)
    const long long SH = (long long)8 * 2048 * 1024;
    f16* slot0 = (f16*)d_ws;
    f16* slot1 = slot0 + SH;
    f16* slot2 = slot0 + 2 * SH;
    f16* slot3 = slot0 + 3 * SH;
    f16* slot4 = slot0 + 4 * SH;
    f16* wh    = slot1;
    f16* Pb    = slot0;            // 8*2048*2048 f16 = 2*SH (slot0 + slot1)

    const int n16w = 1024 * 1024 / 16;
    const long long zero = 0;
    const long long M1 = 1024 * 1024;

    // 0) W -> f16 (into slot1)
    cast3_kernel<<<dim3(64, 1, 3), 256, 0, stream>>>(Wq, Wk, Wv, wh, wh + M1, wh + 2 * M1, n16w);
    // 1) v-proj, f32 A, fused transpose: vT -> slot4  (M=16384 N=1024 K=1024, gx=8)
    gemm_nt_k<1, 1, 1><<<dim3(512, 1, 1), 512, 0, stream>>>(
        (const void*)value, wh + 2 * M1, (void*)slot4, 1024, 1024, 1024, 2048, zero, zero, zero, 8);
    // 2) q-proj, f32 A: q -> slot2
    gemm_nt_k<1, 0, 1><<<dim3(512, 1, 1), 512, 0, stream>>>(
        (const void*)query, wh, (void*)slot2, 1024, 1024, 1024, 1024, zero, zero, zero, 8);
    // 3) k-proj, f32 A: k -> slot3
    gemm_nt_k<1, 0, 1><<<dim3(512, 1, 1), 512, 0, stream>>>(
        (const void*)keyi, wh + M1, (void*)slot3, 1024, 1024, 1024, 1024, zero, zero, zero, 8);
    // 4) S = q @ k^T per batch: M=N=2048 K=1024 -> grid 8*16=128 per z, gx=16
    //    (P overwrites slot0|slot1; wh dead)
    gemm_nt_k<1, 0, 0><<<dim3(128, 1, 8), 512, 0, stream>>>(
        (const void*)slot2, slot3, (void*)Pb, 1024, 1024, 1024, 2048,
        (long long)2048 * 1024, (long long)2048 * 1024, (long long)2048 * 2048, 16);
    // 5) P = masked softmax(S), in place
    softmax_kernel<<<dim3(16384), 256, 0, stream>>>(Pb, mask);
    // 6) context = P @ vT^T: M=2048 N=1024 K=2048 -> grid 8*8=64 per z, gx=8
    gemm_nt_k<0, 0, 0><<<dim3(64, 1, 8), 512, 0, stream>>>(
        (const void*)Pb, slot4, (void*)out, 2048, 2048, 2048, 1024,
        (long long)2048 * 2048, (long long)1024 * 2048, (long long)2048 * 1024, 8);
}

// Round 13
// 354.408 us; speedup vs baseline: 1.7578x; 1.7578x over previous
//
#include <hip/hip_runtime.h>
#include <hip/hip_fp16.h>
#include <math.h>

typedef _Float16 f16;
typedef _Float16 f16x4 __attribute__((ext_vector_type(4)));
typedef _Float16 f16x8 __attribute__((ext_vector_type(8)));
typedef float f32x4 __attribute__((ext_vector_type(4)));

#define GLOAD_LDS16(g, l)                                                                  \
    __builtin_amdgcn_global_load_lds((const __attribute__((address_space(1))) void*)(g),   \
                                     (__attribute__((address_space(3))) void*)(l), 16, 0, 0)

// Three-source f32 -> f16 cast (W only), 16 elems/thread/iter.
__global__ __launch_bounds__(256) void cast3_kernel(const float* __restrict__ s0,
                                                    const float* __restrict__ s1,
                                                    const float* __restrict__ s2,
                                                    f16* d0, f16* d1, f16* d2, int n16each)
{
    const int z = blockIdx.z;
    const float* src = (z == 0) ? s0 : (z == 1) ? s1 : s2;
    f16* dst = (z == 0) ? d0 : (z == 1) ? d1 : d2;
    const int stride = gridDim.x * blockDim.x;
    for (int i = blockIdx.x * blockDim.x + threadIdx.x; i < n16each; i += stride) {
        const float4* sp = (const float4*)(src + (long long)i * 16);
        float4 a = sp[0], b = sp[1], c = sp[2], d4 = sp[3];
        f16x8 lo = {(f16)a.x, (f16)a.y, (f16)a.z, (f16)a.w,
                    (f16)b.x, (f16)b.y, (f16)b.z, (f16)b.w};
        f16x8 hi = {(f16)c.x, (f16)c.y, (f16)c.z, (f16)c.w,
                    (f16)d4.x, (f16)d4.y, (f16)d4.z, (f16)d4.w};
        f16x8* dp = (f16x8*)(dst + (long long)i * 16);
        dp[0] = lo;
        dp[1] = hi;
    }
}

// ============================================================================
// 256x128 tile NT GEMM, BK=64, 512 threads (8 waves 4Mx2N), SINGLE-buffered
// 48 KiB f16 LDS (m97 regime, r10-proven: 953 TF, 0 bank conflicts).
// AREG=0: both operands f16, staged via global_load_lds (linear dest,
//         inverse-swizzled global source) — byte-identical to r10/r11.
// AREG=1: A is f32 in global; UNIFORM register staging: load f32 -> cvt f16
//         in-reg -> ds_write_b128 at the swizzled LDS address (natural global
//         layout; swizzle pair = write+read, rule 21).  B (f16) reg-staged the
//         same way.  LDS layout/frag reads/MFMA identical to AREG=0.
// TRANSC=1: epilogue writes C transposed per-batch (vT[b][o][s]) via LDS retile.
// C[M,N] = A[M,K] * B[N,K](f16)^T.  M % 256 == 0, N % 128 == 0, K % 64 == 0.
// Grid: dim3(nwg, 1, nz), nwg % 8 == 0; gx = N/128.
// ============================================================================
template <int OUTF16, int TRANSC, int AREG>
__global__ __launch_bounds__(512, 2) void gemm_nt_k(
    const void* __restrict__ Ab, const f16* __restrict__ Bb, void* __restrict__ Cb,
    int K, int lda, int ldb, int ldc,
    long long sA, long long sB, long long sC, int gx)
{
    // A: 256 rows x 128B, B: 128 rows x 128B.  TRANSC epilogue reuses as [128][136].
    __shared__ __align__(16) f16 smem[256 * 64 + 128 * 64];
    constexpr int B_OFF_E = 256 * 64;          // f16 elems
    constexpr int B_OFF_B = B_OFF_E * 2;       // bytes

    // XCD-aware bijective swizzle (nwg % 8 == 0).
    const int nwg = gridDim.x;
    const int swz = (blockIdx.x & 7) * (nwg >> 3) + (blockIdx.x >> 3);
    const int bx = swz % gx, by = swz / gx;

    const int z = blockIdx.z;
    constexpr int esz = AREG ? 4 : 2;
    const char* pA = (const char*)Ab + ((long long)z * sA + (long long)by * 256 * lda) * esz;
    const char* pB = (const char*)(Bb + z * sB + (long long)bx * 128 * ldb);
    const long long ldaB = (long long)lda * esz, ldb2 = (long long)ldb * 2;

    const int tid = threadIdx.x;
    const int w = tid >> 6, l = tid & 63;
    const int wr = w >> 1, wc = w & 1;          // 4M x 2N wave grid, wave tile 64x64

    f32x4 acc[4][4];
#pragma unroll
    for (int i = 0; i < 4; i++)
#pragma unroll
        for (int j = 0; j < 4; j++) acc[i][j] = (f32x4){0.f, 0.f, 0.f, 0.f};

    const int lr = l & 15;          // frag row within 16
    const int lkb = (l >> 4) * 16;  // frag k sub-offset in bytes

    // f16 frag reads: addr = row*128 + (kbyte ^ ((row&7)<<4)), kbyte in [0,128).
#define FRAG_A16(row, kbyte)                                                              \
    (*(const f16x8*)((const char*)&smem[0] + ((row) * 128) + ((kbyte) ^ (((row) & 7) << 4))))
#define FRAG_B(row, kbyte)                                                                \
    (*(const f16x8*)((const char*)&smem[0] + B_OFF_B + ((row) * 128) + ((kbyte) ^ (((row) & 7) << 4))))

    const int nt = K >> 6;
    for (int t = 0; t < nt; ++t) {
        if (AREG) {
            // --- A: 4 chunks/thread; chunk c -> row = c>>3, colb = (c&7)*16 (f16 bytes).
            // Global f32 source (natural layout): row*ldaB + (t*64)*4 + colb*2.
            const long long kbA = (long long)t * 256;
#pragma unroll
            for (int i = 0; i < 4; i++) {
                const int c = i * 512 + tid;
                const int row = c >> 3;
                const int colb = (c & 7) * 16;
                const float4* gsrc = (const float4*)(pA + (long long)row * ldaB + kbA + colb * 2);
                float4 lo = gsrc[0], hi = gsrc[1];
                f16x8 v8 = {(f16)lo.x, (f16)lo.y, (f16)lo.z, (f16)lo.w,
                            (f16)hi.x, (f16)hi.y, (f16)hi.z, (f16)hi.w};
                *(f16x8*)((char*)&smem[0] + row * 128 + (colb ^ ((row & 7) << 4))) = v8;
            }
            // --- B: 2 chunks/thread, f16 copy through regs to swizzled addr.
            const long long kbB = (long long)t * 128;
#pragma unroll
            for (int i = 0; i < 2; i++) {
                const int c = i * 512 + tid;
                const int row = c >> 3;
                const int colb = (c & 7) * 16;
                f16x8 v8 = *(const f16x8*)(pB + (long long)row * ldb2 + kbB + colb);
                *(f16x8*)((char*)&smem[0] + B_OFF_B + row * 128 + (colb ^ ((row & 7) << 4))) = v8;
            }
        } else {
            // --- proven gload_lds path: linear LDS dest, inverse-swizzled source.
            const long long kb = (long long)t * 128;
#pragma unroll
            for (int i = 0; i < 4; i++) {
                const int c = i * 512 + tid;
                const int row = c >> 3;
                const int col = ((c & 7) * 16) ^ ((row & 7) << 4);
                GLOAD_LDS16(pA + (long long)row * ldaB + kb + col, &smem[(long long)c * 8]);
            }
#pragma unroll
            for (int i = 0; i < 2; i++) {
                const int c = i * 512 + tid;
                const int row = c >> 3;
                const int col = ((c & 7) * 16) ^ ((row & 7) << 4);
                GLOAD_LDS16(pB + (long long)row * ldb2 + kb + col, &smem[B_OFF_E + (long long)c * 8]);
            }
        }
        __syncthreads();   // drains vmcnt/lgkmcnt + publishes tile

        f16x8 bf[4][2], af[4][2];
#pragma unroll
        for (int fc = 0; fc < 4; fc++)
#pragma unroll
            for (int ks = 0; ks < 2; ks++)
                bf[fc][ks] = FRAG_B(wc * 64 + fc * 16 + lr, ks * 64 + lkb);
#pragma unroll
        for (int fq = 0; fq < 4; fq++)
#pragma unroll
            for (int ks = 0; ks < 2; ks++)
                af[fq][ks] = FRAG_A16(wr * 64 + fq * 16 + lr, ks * 64 + lkb);

#pragma unroll
        for (int fq = 0; fq < 4; fq++)
#pragma unroll
            for (int fc = 0; fc < 4; fc++)
#pragma unroll
                for (int ks = 0; ks < 2; ks++)
                    acc[fq][fc] = __builtin_amdgcn_mfma_f32_16x16x32_f16(
                        af[fq][ks], bf[fc][ks], acc[fq][fc], 0, 0, 0);

        __syncthreads();   // all reads done before next STAGE overwrites
    }
#undef FRAG_A16
#undef FRAG_B

    // C/D 16x16 layout: col = lane&15, row = (lane>>4)*4 + i  (HW-verified)
    const int row_l = (l >> 4) * 4;
    const long long gr0 = (long long)by * 256 + wr * 64;
    const int gc0 = bx * 128 + wc * 64;

    if (TRANSC) {
        // Write vT[b][o][s]; block covers flat rows [by*256,+256) (one batch)
        // and cols [bx*128,+128).  LDS retile [128 o][136 s], 2 passes.
        const long long blk_r0 = (long long)by * 256;
        const int b = (int)(blk_r0 >> 11);
        const int s_base = (int)(blk_r0 & 2047);
        f16* vTp = (f16*)Cb + (long long)b * 1024 * 2048;
#pragma unroll
        for (int h = 0; h < 2; h++) {
            __syncthreads();
            if ((wr >> 1) == h) {
                const int s64 = (wr & 1) * 64;
#pragma unroll
                for (int fq = 0; fq < 4; fq++)
#pragma unroll
                    for (int fc = 0; fc < 4; fc++)
#pragma unroll
                        for (int i = 0; i < 4; i++)
                            smem[(wc * 64 + fc * 16 + lr) * 136 + s64 + fq * 16 + row_l + i] =
                                (f16)acc[fq][fc][i];
            }
            __syncthreads();
#pragma unroll
            for (int j = 0; j < 4; j++) {
                const int c = j * 512 + tid;
                const int o = c >> 4, s8 = (c & 15) * 8;
                f16x8 vv = *(const f16x8*)&smem[o * 136 + s8];
                *(f16x8*)&vTp[((long long)(bx * 128 + o)) * 2048 + s_base + h * 128 + s8] = vv;
            }
        }
    } else if (OUTF16) {
        f16* C = (f16*)Cb + z * sC;
#pragma unroll
        for (int fq = 0; fq < 4; fq++)
#pragma unroll
            for (int fc = 0; fc < 4; fc++)
#pragma unroll
                for (int i = 0; i < 4; i++)
                    C[(gr0 + fq * 16 + row_l + i) * ldc + gc0 + fc * 16 + lr] = (f16)acc[fq][fc][i];
    } else {
        float* C = (float*)Cb + z * sC;
#pragma unroll
        for (int fq = 0; fq < 4; fq++)
#pragma unroll
            for (int fc = 0; fc < 4; fc++)
#pragma unroll
                for (int i = 0; i < 4; i++)
                    C[(gr0 + fq * 16 + row_l + i) * ldc + gc0 + fc * 16 + lr] = acc[fq][fc][i];
    }
}

__device__ __forceinline__ float wred_max(float v) {
#pragma unroll
    for (int o = 32; o > 0; o >>= 1) v = fmaxf(v, __shfl_xor(v, o));
    return v;
}
__device__ __forceinline__ float wred_sum(float v) {
#pragma unroll
    for (int o = 32; o > 0; o >>= 1) v += __shfl_xor(v, o);
    return v;
}

// In-place masked softmax over each 2048-wide score row (fp16).
__global__ __launch_bounds__(256) void softmax_kernel(f16* __restrict__ Sm, const int* __restrict__ mask)
{
    const long long row = blockIdx.x;
    const int b = (int)(row >> 11);
    f16* Srow = Sm + row * 2048;
    const int* mrow = mask + b * 2048;
    const int t = threadIdx.x;
    const int w = t >> 6, l = t & 63;

    f16x8 sv = *(const f16x8*)(Srow + t * 8);
    int4 m0 = *(const int4*)(mrow + t * 8);
    int4 m1 = *(const int4*)(mrow + t * 8 + 4);
    int mk[8] = {m0.x, m0.y, m0.z, m0.w, m1.x, m1.y, m1.z, m1.w};
    float v[8];
#pragma unroll
    for (int j = 0; j < 8; j++) v[j] = (float)sv[j];

    float mx = -INFINITY;
#pragma unroll
    for (int j = 0; j < 8; j++) if (mk[j]) mx = fmaxf(mx, v[j]);
    mx = wred_max(mx);
    __shared__ float redm[4], reds[4];
    if (l == 0) redm[w] = mx;
    __syncthreads();
    mx = fmaxf(fmaxf(redm[0], redm[1]), fmaxf(redm[2], redm[3]));

    if (mx == -INFINITY) {
        // reference: all scores == MASK_FILL -> softmax is exactly uniform
        const f16 u = (f16)(1.0f / 2048.0f);
        f16x8 pv;
#pragma unroll
        for (int j = 0; j < 8; j++) pv[j] = u;
        *(f16x8*)(Srow + t * 8) = pv;
        return;
    }

    float e[8];
    float s = 0.f;
#pragma unroll
    for (int j = 0; j < 8; j++) { e[j] = mk[j] ? expf(v[j] - mx) : 0.f; s += e[j]; }
    s = wred_sum(s);
    if (l == 0) reds[w] = s;
    __syncthreads();
    s = reds[0] + reds[1] + reds[2] + reds[3];
    const float inv = 1.0f / s;
    f16x8 pv;
#pragma unroll
    for (int j = 0; j < 8; j++) pv[j] = (f16)(e[j] * inv);
    *(f16x8*)(Srow + t * 8) = pv;
}

extern "C" void kernel_launch(void* const* d_in, const int* in_sizes, int n_in,
                              void* d_out, int out_size, void* d_ws, size_t ws_size,
                              hipStream_t stream)
{
    const float* query = (const float*)d_in[0];
    const float* keyi  = (const float*)d_in[1];
    const float* value = (const float*)d_in[2];
    const float* Wq    = (const float*)d_in[3];
    const float* Wk    = (const float*)d_in[4];
    const float* Wv    = (const float*)d_in[5];
    const int*   mask  = (const int*)d_in[6];
    float* out = (float*)d_out;

    // ws: 5 slots of SH f16 = 167.8 MB.  X casts eliminated — projections read
    // the f32 inputs directly (AREG reg-staged cvt).
    //   slot0: P-low ; slot1: wh (6 MB, dead after k-proj) -> P-high ;
    //   slot2: q ; slot3: k ; slot4: vT (v-proj TRANSC epilogue)
    const long long SH = (long long)8 * 2048 * 1024;
    f16* slot0 = (f16*)d_ws;
    f16* slot1 = slot0 + SH;
    f16* slot2 = slot0 + 2 * SH;
    f16* slot3 = slot0 + 3 * SH;
    f16* slot4 = slot0 + 4 * SH;
    f16* wh    = slot1;
    f16* Pb    = slot0;            // 8*2048*2048 f16 = 2*SH (slot0 + slot1)

    const int n16w = 1024 * 1024 / 16;
    const long long zero = 0;
    const long long M1 = 1024 * 1024;

    // 0) W -> f16 (into slot1)
    cast3_kernel<<<dim3(64, 1, 3), 256, 0, stream>>>(Wq, Wk, Wv, wh, wh + M1, wh + 2 * M1, n16w);
    // 1) v-proj (f32 A reg-staged, fused transpose): vT -> slot4
    gemm_nt_k<1, 1, 1><<<dim3(512, 1, 1), 512, 0, stream>>>(
        (const void*)value, wh + 2 * M1, (void*)slot4, 1024, 1024, 1024, 2048, zero, zero, zero, 8);
    // 2) q-proj (f32 A reg-staged): q -> slot2
    gemm_nt_k<1, 0, 1><<<dim3(512, 1, 1), 512, 0, stream>>>(
        (const void*)query, wh, (void*)slot2, 1024, 1024, 1024, 1024, zero, zero, zero, 8);
    // 3) k-proj (f32 A reg-staged): k -> slot3
    gemm_nt_k<1, 0, 1><<<dim3(512, 1, 1), 512, 0, stream>>>(
        (const void*)keyi, wh + M1, (void*)slot3, 1024, 1024, 1024, 1024, zero, zero, zero, 8);
    // 4) S = q @ k^T per batch (proven gload_lds arm): P over slot0|slot1 (wh dead)
    gemm_nt_k<1, 0, 0><<<dim3(128, 1, 8), 512, 0, stream>>>(
        (const void*)slot2, slot3, (void*)Pb, 1024, 1024, 1024, 2048,
        (long long)2048 * 1024, (long long)2048 * 1024, (long long)2048 * 2048, 16);
    // 5) P = masked softmax(S), in place
    softmax_kernel<<<dim3(16384), 256, 0, stream>>>(Pb, mask);
    // 6) context = P @ vT^T (proven gload_lds arm, f32 out)
    gemm_nt_k<0, 0, 0><<<dim3(64, 1, 8), 512, 0, stream>>>(
        (const void*)Pb, slot4, (void*)out, 2048, 2048, 2048, 1024,
        (long long)2048 * 2048, (long long)1024 * 2048, (long long)2048 * 1024, 8);
}

// Round 14
// 323.914 us; speedup vs baseline: 1.9233x; 1.0941x over previous
//
#include <hip/hip_runtime.h>
#include <hip/hip_fp16.h>
#include <math.h>

typedef _Float16 f16;
typedef _Float16 f16x4 __attribute__((ext_vector_type(4)));
typedef _Float16 f16x8 __attribute__((ext_vector_type(8)));
typedef float f32x4 __attribute__((ext_vector_type(4)));

#define GLOAD_LDS16(g, l)                                                                  \
    __builtin_amdgcn_global_load_lds((const __attribute__((address_space(1))) void*)(g),   \
                                     (__attribute__((address_space(3))) void*)(l), 16, 0, 0)

// Three-source f32 -> f16 cast, 16 elems/thread/iter (r11-proven).
__global__ __launch_bounds__(256) void cast3_kernel(const float* __restrict__ s0,
                                                    const float* __restrict__ s1,
                                                    const float* __restrict__ s2,
                                                    f16* d0, f16* d1, f16* d2, int n16each)
{
    const int z = blockIdx.z;
    const float* src = (z == 0) ? s0 : (z == 1) ? s1 : s2;
    f16* dst = (z == 0) ? d0 : (z == 1) ? d1 : d2;
    const int stride = gridDim.x * blockDim.x;
    for (int i = blockIdx.x * blockDim.x + threadIdx.x; i < n16each; i += stride) {
        const float4* sp = (const float4*)(src + (long long)i * 16);
        float4 a = sp[0], b = sp[1], c = sp[2], d4 = sp[3];
        f16x8 lo = {(f16)a.x, (f16)a.y, (f16)a.z, (f16)a.w,
                    (f16)b.x, (f16)b.y, (f16)b.z, (f16)b.w};
        f16x8 hi = {(f16)c.x, (f16)c.y, (f16)c.z, (f16)c.w,
                    (f16)d4.x, (f16)d4.y, (f16)d4.z, (f16)d4.w};
        f16x8* dp = (f16x8*)(dst + (long long)i * 16);
        dp[0] = lo;
        dp[1] = hi;
    }
}

// Transpose-cast for W: dst[h][o] = (f16)src[o][h], 1024x1024.  blockIdx.z
// selects (Wq->dA) / (Wk->dB).  64x64 LDS tiles (transpose_v-proven pattern).
__global__ __launch_bounds__(256) void transcast_w_kernel(const float* __restrict__ Wq,
                                                          const float* __restrict__ Wk,
                                                          f16* __restrict__ dA,
                                                          f16* __restrict__ dB)
{
    __shared__ f16 tile[64][72];
    const float* src = blockIdx.z ? Wk : Wq;
    f16* dst = blockIdx.z ? dB : dA;
    const int h0 = blockIdx.x * 64, o0 = blockIdx.y * 64;
    const int t = threadIdx.x;
    const int r = t >> 2, c = (t & 3) * 16;
    const float* sp = src + (long long)(o0 + r) * 1024 + h0 + c;
    float4 v0 = *(const float4*)(sp + 0);
    float4 v1 = *(const float4*)(sp + 4);
    float4 v2 = *(const float4*)(sp + 8);
    float4 v3 = *(const float4*)(sp + 12);
    *(f16x4*)&tile[r][c]      = (f16x4){(f16)v0.x, (f16)v0.y, (f16)v0.z, (f16)v0.w};
    *(f16x4*)&tile[r][c + 4]  = (f16x4){(f16)v1.x, (f16)v1.y, (f16)v1.z, (f16)v1.w};
    *(f16x4*)&tile[r][c + 8]  = (f16x4){(f16)v2.x, (f16)v2.y, (f16)v2.z, (f16)v2.w};
    *(f16x4*)&tile[r][c + 12] = (f16x4){(f16)v3.x, (f16)v3.y, (f16)v3.z, (f16)v3.w};
    __syncthreads();
    f16 buf[16];
#pragma unroll
    for (int j = 0; j < 16; j++) buf[j] = tile[c + j][r];
    f16* dp = dst + (long long)(h0 + r) * 1024 + o0 + c;
    *(f16x8*)(dp)     = *(f16x8*)&buf[0];
    *(f16x8*)(dp + 8) = *(f16x8*)&buf[8];
}

// ============================================================================
// 256x128 tile NT GEMM, BK=64, 512 threads (8 waves 4Mx2N), SINGLE-buffered
// 48 KiB f16 LDS (m97 regime, r10/r11-proven: 953 TF, 0 bank conflicts).
// Both operands f16 via global_load_lds (linear dest, inverse-swizzled source).
// TRANSC=1: epilogue writes C transposed per-batch (vT[b][o][s]) via LDS retile.
// C[M,N] = A[M,K](f16) * B[N,K](f16)^T.  M % 256 == 0, N % 128 == 0, K % 64 == 0.
// Grid: dim3(nwg, 1, nz), nwg % 8 == 0; gx = N/128.
// ============================================================================
template <int OUTF16, int TRANSC>
__global__ __launch_bounds__(512, 2) void gemm_nt_k(
    const f16* __restrict__ Ab, const f16* __restrict__ Bb, void* __restrict__ Cb,
    int K, int lda, int ldb, int ldc,
    long long sA, long long sB, long long sC, int gx)
{
    // A: 256 rows x 128B, B: 128 rows x 128B.  TRANSC epilogue reuses as [128][136].
    __shared__ __align__(16) f16 smem[256 * 64 + 128 * 64];
    constexpr int B_OFF_E = 256 * 64;
    constexpr int B_OFF_B = B_OFF_E * 2;

    // XCD-aware bijective swizzle (nwg % 8 == 0).
    const int nwg = gridDim.x;
    const int swz = (blockIdx.x & 7) * (nwg >> 3) + (blockIdx.x >> 3);
    const int bx = swz % gx, by = swz / gx;

    const int z = blockIdx.z;
    const char* pA = (const char*)(Ab + z * sA + (long long)by * 256 * lda);
    const char* pB = (const char*)(Bb + z * sB + (long long)bx * 128 * ldb);
    const long long lda2 = (long long)lda * 2, ldb2 = (long long)ldb * 2;

    const int tid = threadIdx.x;
    const int w = tid >> 6, l = tid & 63;
    const int wr = w >> 1, wc = w & 1;          // 4M x 2N wave grid, wave tile 64x64

    f32x4 acc[4][4];
#pragma unroll
    for (int i = 0; i < 4; i++)
#pragma unroll
        for (int j = 0; j < 4; j++) acc[i][j] = (f32x4){0.f, 0.f, 0.f, 0.f};

    const int lr = l & 15;
    const int lkb = (l >> 4) * 16;

#define FRAG_A16(row, kbyte)                                                              \
    (*(const f16x8*)((const char*)&smem[0] + ((row) * 128) + ((kbyte) ^ (((row) & 7) << 4))))
#define FRAG_B(row, kbyte)                                                                \
    (*(const f16x8*)((const char*)&smem[0] + B_OFF_B + ((row) * 128) + ((kbyte) ^ (((row) & 7) << 4))))

    const int nt = K >> 6;
    for (int t = 0; t < nt; ++t) {
        const long long kb = (long long)t * 128;
#pragma unroll
        for (int i = 0; i < 4; i++) {
            const int c = i * 512 + tid;
            const int row = c >> 3;
            const int col = ((c & 7) * 16) ^ ((row & 7) << 4);
            GLOAD_LDS16(pA + (long long)row * lda2 + kb + col, &smem[(long long)c * 8]);
        }
#pragma unroll
        for (int i = 0; i < 2; i++) {
            const int c = i * 512 + tid;
            const int row = c >> 3;
            const int col = ((c & 7) * 16) ^ ((row & 7) << 4);
            GLOAD_LDS16(pB + (long long)row * ldb2 + kb + col, &smem[B_OFF_E + (long long)c * 8]);
        }
        __syncthreads();

        f16x8 bf[4][2], af[4][2];
#pragma unroll
        for (int fc = 0; fc < 4; fc++)
#pragma unroll
            for (int ks = 0; ks < 2; ks++)
                bf[fc][ks] = FRAG_B(wc * 64 + fc * 16 + lr, ks * 64 + lkb);
#pragma unroll
        for (int fq = 0; fq < 4; fq++)
#pragma unroll
            for (int ks = 0; ks < 2; ks++)
                af[fq][ks] = FRAG_A16(wr * 64 + fq * 16 + lr, ks * 64 + lkb);

#pragma unroll
        for (int fq = 0; fq < 4; fq++)
#pragma unroll
            for (int fc = 0; fc < 4; fc++)
#pragma unroll
                for (int ks = 0; ks < 2; ks++)
                    acc[fq][fc] = __builtin_amdgcn_mfma_f32_16x16x32_f16(
                        af[fq][ks], bf[fc][ks], acc[fq][fc], 0, 0, 0);

        __syncthreads();
    }
#undef FRAG_A16
#undef FRAG_B

    // C/D 16x16 layout: col = lane&15, row = (lane>>4)*4 + i  (HW-verified)
    const int row_l = (l >> 4) * 4;
    const long long gr0 = (long long)by * 256 + wr * 64;
    const int gc0 = bx * 128 + wc * 64;

    if (TRANSC) {
        const long long blk_r0 = (long long)by * 256;
        const int b = (int)(blk_r0 >> 11);
        const int s_base = (int)(blk_r0 & 2047);
        f16* vTp = (f16*)Cb + (long long)b * 1024 * 2048;
#pragma unroll
        for (int h = 0; h < 2; h++) {
            __syncthreads();
            if ((wr >> 1) == h) {
                const int s64 = (wr & 1) * 64;
#pragma unroll
                for (int fq = 0; fq < 4; fq++)
#pragma unroll
                    for (int fc = 0; fc < 4; fc++)
#pragma unroll
                        for (int i = 0; i < 4; i++)
                            smem[(wc * 64 + fc * 16 + lr) * 136 + s64 + fq * 16 + row_l + i] =
                                (f16)acc[fq][fc][i];
            }
            __syncthreads();
#pragma unroll
            for (int j = 0; j < 4; j++) {
                const int c = j * 512 + tid;
                const int o = c >> 4, s8 = (c & 15) * 8;
                f16x8 vv = *(const f16x8*)&smem[o * 136 + s8];
                *(f16x8*)&vTp[((long long)(bx * 128 + o)) * 2048 + s_base + h * 128 + s8] = vv;
            }
        }
    } else if (OUTF16) {
        f16* C = (f16*)Cb + z * sC;
#pragma unroll
        for (int fq = 0; fq < 4; fq++)
#pragma unroll
            for (int fc = 0; fc < 4; fc++)
#pragma unroll
                for (int i = 0; i < 4; i++)
                    C[(gr0 + fq * 16 + row_l + i) * ldc + gc0 + fc * 16 + lr] = (f16)acc[fq][fc][i];
    } else {
        float* C = (float*)Cb + z * sC;
#pragma unroll
        for (int fq = 0; fq < 4; fq++)
#pragma unroll
            for (int fc = 0; fc < 4; fc++)
#pragma unroll
                for (int i = 0; i < 4; i++)
                    C[(gr0 + fq * 16 + row_l + i) * ldc + gc0 + fc * 16 + lr] = acc[fq][fc][i];
    }
}

__device__ __forceinline__ float wred_max(float v) {
#pragma unroll
    for (int o = 32; o > 0; o >>= 1) v = fmaxf(v, __shfl_xor(v, o));
    return v;
}
__device__ __forceinline__ float wred_sum(float v) {
#pragma unroll
    for (int o = 32; o > 0; o >>= 1) v += __shfl_xor(v, o);
    return v;
}

// In-place masked softmax over each 2048-wide score row (fp16).
__global__ __launch_bounds__(256) void softmax_kernel(f16* __restrict__ Sm, const int* __restrict__ mask)
{
    const long long row = blockIdx.x;
    const int b = (int)(row >> 11);
    f16* Srow = Sm + row * 2048;
    const int* mrow = mask + b * 2048;
    const int t = threadIdx.x;
    const int w = t >> 6, l = t & 63;

    f16x8 sv = *(const f16x8*)(Srow + t * 8);
    int4 m0 = *(const int4*)(mrow + t * 8);
    int4 m1 = *(const int4*)(mrow + t * 8 + 4);
    int mk[8] = {m0.x, m0.y, m0.z, m0.w, m1.x, m1.y, m1.z, m1.w};
    float v[8];
#pragma unroll
    for (int j = 0; j < 8; j++) v[j] = (float)sv[j];

    float mx = -INFINITY;
#pragma unroll
    for (int j = 0; j < 8; j++) if (mk[j]) mx = fmaxf(mx, v[j]);
    mx = wred_max(mx);
    __shared__ float redm[4], reds[4];
    if (l == 0) redm[w] = mx;
    __syncthreads();
    mx = fmaxf(fmaxf(redm[0], redm[1]), fmaxf(redm[2], redm[3]));

    if (mx == -INFINITY) {
        // reference: all scores == MASK_FILL -> softmax is exactly uniform
        const f16 u = (f16)(1.0f / 2048.0f);
        f16x8 pv;
#pragma unroll
        for (int j = 0; j < 8; j++) pv[j] = u;
        *(f16x8*)(Srow + t * 8) = pv;
        return;
    }

    float e[8];
    float s = 0.f;
#pragma unroll
    for (int j = 0; j < 8; j++) { e[j] = mk[j] ? expf(v[j] - mx) : 0.f; s += e[j]; }
    s = wred_sum(s);
    if (l == 0) reds[w] = s;
    __syncthreads();
    s = reds[0] + reds[1] + reds[2] + reds[3];
    const float inv = 1.0f / s;
    f16x8 pv;
#pragma unroll
    for (int j = 0; j < 8; j++) pv[j] = (f16)(e[j] * inv);
    *(f16x8*)(Srow + t * 8) = pv;
}

extern "C" void kernel_launch(void* const* d_in, const int* in_sizes, int n_in,
                              void* d_out, int out_size, void* d_ws, size_t ws_size,
                              hipStream_t stream)
{
    const float* query = (const float*)d_in[0];
    const float* keyi  = (const float*)d_in[1];
    const float* value = (const float*)d_in[2];
    const float* Wq    = (const float*)d_in[3];
    const float* Wk    = (const float*)d_in[4];
    const float* Wv    = (const float*)d_in[5];
    const int*   mask  = (const int*)d_in[6];
    float* out = (float*)d_out;

    // Algebraic restructure: S = Xq (Wq^T Wk) Xk^T.  With M = Wq^T Wk (f16):
    //   k' = Xk @ M^T  (NT with B = M) ;  S = Xq @ k'^T  — q-projection GONE.
    // ws: 5 slots of SH f16 = 167.8 MB.  Lifetimes:
    //   slot0: Xk (dead after k'-proj) -> P-low
    //   slot1: wh = [WqT|WkT|Wv|M] f16 (8 MB, dead after k'-proj) -> P-high
    //   slot2: Xq (live until S-GEMM)
    //   slot3: Xv (dead after v-proj) -> k'
    //   slot4: vT (v-proj TRANSC epilogue)
    const long long SH = (long long)8 * 2048 * 1024;
    f16* slot0 = (f16*)d_ws;
    f16* slot1 = slot0 + SH;
    f16* slot2 = slot0 + 2 * SH;
    f16* slot3 = slot0 + 3 * SH;
    f16* slot4 = slot0 + 4 * SH;
    const long long M1 = 1024 * 1024;
    f16* whA = slot1;            // WqT f16  [h][o]
    f16* whB = slot1 + M1;       // WkT f16  [h][o]
    f16* whC = slot1 + 2 * M1;   // Wv  f16  [o][h]
    f16* whD = slot1 + 3 * M1;   // M = Wq^T Wk, f16 [j][h]
    f16* Pb  = slot0;            // 8*2048*2048 f16 = 2*SH (slot0 + slot1)

    const int n16x = (int)(SH / 16);
    const int n16w = (int)(M1 / 16);
    const long long zero = 0;

    // 0) WqT, WkT (transpose-cast) ; Wv plain cast
    transcast_w_kernel<<<dim3(16, 16, 2), 256, 0, stream>>>(Wq, Wk, whA, whB);
    cast3_kernel<<<dim3(64, 1, 1), 256, 0, stream>>>(Wv, Wv, Wv, whC, whC, whC, n16w);
    // 1) M(j,h) = sum_o WqT(j,o)*WkT(h,o) = (Wq^T Wk)(j,h): NT(WqT, WkT) -> whD
    gemm_nt_k<1, 0><<<dim3(32, 1, 1), 512, 0, stream>>>(
        whA, whB, (void*)whD, 1024, 1024, 1024, 1024, zero, zero, zero, 8);
    // 2) X casts: Xq -> slot2, Xk -> slot0, Xv -> slot3
    cast3_kernel<<<dim3(1024, 1, 3), 256, 0, stream>>>(query, keyi, value, slot2, slot0, slot3, n16x);
    // 3) v-proj with fused transpose: vT -> slot4  (A = Xv, B = Wv)
    gemm_nt_k<1, 1><<<dim3(512, 1, 1), 512, 0, stream>>>(
        slot3, whC, (void*)slot4, 1024, 1024, 1024, 2048, zero, zero, zero, 8);
    // 4) k' = Xk @ M^T: NT(A = Xk slot0, B = M whD) -> slot3 (Xv dead)
    gemm_nt_k<1, 0><<<dim3(512, 1, 1), 512, 0, stream>>>(
        slot0, whD, (void*)slot3, 1024, 1024, 1024, 1024, zero, zero, zero, 8);
    // 5) S = Xq @ k'^T per batch -> P (slot0|slot1; Xk and wh dead)
    gemm_nt_k<1, 0><<<dim3(128, 1, 8), 512, 0, stream>>>(
        slot2, slot3, (void*)Pb, 1024, 1024, 1024, 2048,
        (long long)2048 * 1024, (long long)2048 * 1024, (long long)2048 * 2048, 16);
    // 6) P = masked softmax(S), in place
    softmax_kernel<<<dim3(16384), 256, 0, stream>>>(Pb, mask);
    // 7) context = P @ vT^T  (f32 out)
    gemm_nt_k<0, 0><<<dim3(64, 1, 8), 512, 0, stream>>>(
        Pb, slot4, (void*)out, 2048, 2048, 2048, 1024,
        (long long)2048 * 2048, (long long)1024 * 2048, (long long)2048 * 1024, 8);
}